// Round 1
// baseline (107.294 us; speedup 1.0000x reference)
//
#include <hip/hip_runtime.h>

// Weighted Chamfer distance, B=4, N=M=8192, D=3.
// out = (1/B) * [ sum_b sum_n w[b,n]*min_m d2  +  sum_b sum_m min_n d2 ]
// Trick: min_m d2(q,t) = q^2 + min_m (t^2 - 2 q.t); with a = -2q the inner
// term is 3 fma + 1 min per pair (4 VALU ops/pair).

#define BB 4
#define NP 8192                 // N == M
#define CHUNKS 8
#define CHUNK (NP / CHUNKS)     // 1024 DB points per block (16 KB LDS as float4)
#define SQ 4                    // queries per thread
#define QBLK (256 * SQ)         // 1024 queries per block
#define QBLOCKS (NP / QBLK)     // 8

// ---------------- prep: pack clouds as float4(x,y,z,|p|^2), zero out ----------------
__global__ __launch_bounds__(256) void prep_kernel(
    const float* __restrict__ src, const float* __restrict__ tgt,
    float4* __restrict__ packedS, float4* __restrict__ packedT,
    float* __restrict__ out)
{
    int gid = blockIdx.x * 256 + threadIdx.x;   // 0 .. 2*BB*NP-1
    int which = gid >> 15;                      // 0 = source, 1 = target
    int idx = gid & (BB * NP - 1);
    const float* c = which ? tgt : src;
    float x = c[idx * 3 + 0];
    float y = c[idx * 3 + 1];
    float z = c[idx * 3 + 2];
    float4 v = make_float4(x, y, z, x * x + y * y + z * z);
    if (which) packedT[idx] = v; else packedS[idx] = v;
    if (gid == 0) out[0] = 0.0f;
}

// ---------------- scan: per-chunk partial mins of e = t^2 - 2 q.t ----------------
__global__ __launch_bounds__(256) void scan_kernel(
    const float4* __restrict__ packedS, const float4* __restrict__ packedT,
    float* __restrict__ partial)
{
    __shared__ float4 tile[CHUNK];
    const int tid = threadIdx.x;
    const int dir = blockIdx.z;                  // 0: queries=source, DB=target
    const int b   = blockIdx.y;
    const int qb  = blockIdx.x >> 3;             // CHUNKS == 8
    const int ch  = blockIdx.x & (CHUNKS - 1);

    const float4* db = (dir == 0 ? packedT : packedS) + b * NP + ch * CHUNK;
    const float4* qc = (dir == 0 ? packedS : packedT) + b * NP + qb * QBLK;

    // stage DB chunk into LDS (coalesced float4 loads)
    for (int i = tid; i < CHUNK; i += 256) tile[i] = db[i];

    // load this thread's queries, pre-scale by -2
    float ax[SQ], ay[SQ], az[SQ], m[SQ];
#pragma unroll
    for (int s = 0; s < SQ; s++) {
        float4 q = qc[tid + s * 256];
        ax[s] = -2.0f * q.x;
        ay[s] = -2.0f * q.y;
        az[s] = -2.0f * q.z;
        m[s]  = 1e30f;
    }
    __syncthreads();

#pragma unroll 8
    for (int j = 0; j < CHUNK; j++) {
        float4 t = tile[j];                      // broadcast ds_read_b128
#pragma unroll
        for (int s = 0; s < SQ; s++) {
            float e = fmaf(ax[s], t.x, t.w);
            e = fmaf(ay[s], t.y, e);
            e = fmaf(az[s], t.z, e);
            m[s] = fminf(m[s], e);
        }
    }

    float* p = partial + ((dir * BB + b) * CHUNKS + ch) * NP + qb * QBLK + tid;
#pragma unroll
    for (int s = 0; s < SQ; s++) p[s * 256] = m[s];
}

// ---------------- reduce: combine chunks, weight, sum, atomicAdd ----------------
__global__ __launch_bounds__(256) void reduce_kernel(
    const float4* __restrict__ packedS, const float4* __restrict__ packedT,
    const float* __restrict__ weights, const float* __restrict__ partial,
    float* __restrict__ out)
{
    const int tid = threadIdx.x;
    const int gid = blockIdx.x * 256 + tid;      // 0 .. 2*BB*NP-1
    const int dir = gid >> 15;
    const int r   = gid & (BB * NP - 1);         // b*NP + q
    const int b   = r >> 13;
    const int q   = r & (NP - 1);

    const float* p = partial + ((dir * BB + b) * CHUNKS) * NP + q;
    float mn = p[0];
#pragma unroll
    for (int ch = 1; ch < CHUNKS; ch++) mn = fminf(mn, p[ch * NP]);

    float q2 = (dir == 0 ? packedS : packedT)[r].w;
    float w  = (dir == 0) ? weights[r] : 1.0f;
    float contrib = (q2 + mn) * w * (1.0f / BB);

    // wave64 shuffle reduction, then cross-wave via LDS
    float v = contrib;
#pragma unroll
    for (int off = 32; off > 0; off >>= 1) v += __shfl_down(v, off, 64);

    __shared__ float ls[4];
    int lane = tid & 63, wave = tid >> 6;
    if (lane == 0) ls[wave] = v;
    __syncthreads();
    if (tid == 0) {
        float s = ls[0] + ls[1] + ls[2] + ls[3];
        atomicAdd(out, s);
    }
}

extern "C" void kernel_launch(void* const* d_in, const int* in_sizes, int n_in,
                              void* d_out, int out_size, void* d_ws, size_t ws_size,
                              hipStream_t stream) {
    const float* src = (const float*)d_in[0];   // (B, N, 3) f32
    const float* tgt = (const float*)d_in[1];   // (B, M, 3) f32
    const float* wgt = (const float*)d_in[2];   // (B, N)    f32
    float* out = (float*)d_out;                 // scalar f32

    char* ws = (char*)d_ws;
    float4* packedS = (float4*)ws;                                   // 512 KB
    float4* packedT = (float4*)(ws + (size_t)BB * NP * 16);          // 512 KB
    float*  partial = (float*)(ws + (size_t)2 * BB * NP * 16);       // 2 MB

    prep_kernel<<<dim3(2 * BB * NP / 256), dim3(256), 0, stream>>>(
        src, tgt, packedS, packedT, out);
    scan_kernel<<<dim3(QBLOCKS * CHUNKS, BB, 2), dim3(256), 0, stream>>>(
        packedS, packedT, partial);
    reduce_kernel<<<dim3(2 * BB * NP / 256), dim3(256), 0, stream>>>(
        packedS, packedT, wgt, partial, out);
}